// Round 1
// baseline (4595.427 us; speedup 1.0000x reference)
//
#include <hip/hip_runtime.h>
#include <hip/hip_bf16.h>

// RGCN 2-layer graph encoder, f32 correctness-first implementation.
// N=50000 nodes, E=1200000 edges, R=40 relations, B=30 bases,
// EMB=64 -> HID=128 -> HID=128, G=64 graphs, mean pool.
//
// Identity used: einsum('nri,rio->no', mean_agg, W) ==
//   sum over edges e into n of (h[src[e]] @ W_{etype[e]}) / cnt[n, etype[e]]
// (linear, so per-edge transform + scaled scatter-add is exact up to fp order).

#define N_NODES 50000
#define N_EDGES 1200000
#define N_REL   40
#define N_BASES 30
#define EMB     64
#define HID     128
#define N_GRAPHS 64

// ---------------- workspace layout (floats) ----------------
#define OFF_W1    ((size_t)0)                         // 40*64*128   = 327680
#define OFF_W2    (OFF_W1 + (size_t)N_REL*EMB*HID)    // 40*128*128  = 655360
#define OFF_CNT   (OFF_W2 + (size_t)N_REL*HID*HID)    // N*R         = 2000000
#define OFF_H1    (OFF_CNT + (size_t)N_NODES*N_REL)   // N*HID       = 6400000
#define OFF_H2    (OFF_H1 + (size_t)N_NODES*HID)      // N*HID       = 6400000
#define OFF_CNTG  (OFF_H2 + (size_t)N_NODES*HID)      // G           = 64
#define OFF_POOL  (OFF_CNTG + N_GRAPHS)               // G*HID       = 8192
#define WS_FLOATS (OFF_POOL + (size_t)N_GRAPHS*HID)

// W[r,i,o] = sum_b comp[r,b] * basis[b,i,o];  IO = in*out
__global__ void k_compute_W(const float* __restrict__ comp,
                            const float* __restrict__ basis,
                            float* __restrict__ W, int IO) {
    int idx = blockIdx.x * blockDim.x + threadIdx.x;
    int total = N_REL * IO;
    if (idx >= total) return;
    int r = idx / IO, io = idx - r * IO;
    float s = 0.f;
#pragma unroll
    for (int b = 0; b < N_BASES; ++b)
        s += comp[r * N_BASES + b] * basis[(size_t)b * IO + io];
    W[idx] = s;
}

__global__ void k_count(const int* __restrict__ dst, const int* __restrict__ etype,
                        float* __restrict__ cnt) {
    int e = blockIdx.x * blockDim.x + threadIdx.x;
    if (e >= N_EDGES) return;
    atomicAdd(&cnt[(size_t)dst[e] * N_REL + etype[e]], 1.0f);
}

// h_acc[n, o] = bias[o] + sum_i hin[row(n), i] * root[i, o]   (o = 0..127)
template <int IN>
__global__ void k_root(const float* __restrict__ hin, const int* __restrict__ xmap,
                       const float* __restrict__ root, const float* __restrict__ bias,
                       float* __restrict__ hacc) {
    int n = blockIdx.x;
    int o = threadIdx.x;  // 128 threads
    int row = xmap ? xmap[n] : n;
    const float* hr = hin + (size_t)row * IN;
    float s = bias[o];
#pragma unroll 8
    for (int i = 0; i < IN; ++i)
        s = fmaf(hr[i], root[i * HID + o], s);
    hacc[(size_t)n * HID + o] = s;
}

// per edge: msg = h[src] @ W_r, scaled by 1/cnt(dst,rel), atomic scatter to dst
template <int IN>
__global__ void k_edge(const float* __restrict__ hin, const int* __restrict__ xmap,
                       const int* __restrict__ src, const int* __restrict__ dst,
                       const int* __restrict__ etype, const float* __restrict__ W,
                       const float* __restrict__ cnt, float* __restrict__ hacc) {
    int o = threadIdx.x;  // 128 threads, one output column each
    for (int e = blockIdx.x; e < N_EDGES; e += gridDim.x) {
        int s = src[e], d = dst[e], r = etype[e];
        int row = xmap ? xmap[s] : s;
        const float* hr = hin + (size_t)row * IN;
        const float* Wr = W + (size_t)r * IN * HID;
        float m = 0.f;
#pragma unroll 8
        for (int i = 0; i < IN; ++i)
            m = fmaf(hr[i], Wr[i * HID + o], m);
        float c = cnt[(size_t)d * N_REL + r];
        float inv = 1.0f / fmaxf(c, 1.0f);
        atomicAdd(&hacc[(size_t)d * HID + o], m * inv);
    }
}

__global__ void k_relu(float* __restrict__ h, size_t n) {
    size_t i = (size_t)blockIdx.x * blockDim.x + threadIdx.x;
    if (i < n) h[i] = fmaxf(h[i], 0.0f);
}

__global__ void k_gcount(const int* __restrict__ batch, float* __restrict__ cntG) {
    int n = blockIdx.x * blockDim.x + threadIdx.x;
    if (n >= N_NODES) return;
    atomicAdd(&cntG[batch[n]], 1.0f);
}

// batch is sorted: running sum per column, flush on graph change.
__global__ void k_pool(const float* __restrict__ h, const int* __restrict__ batch,
                       float* __restrict__ acc) {
    const int CH = 512;
    int n0 = blockIdx.x * CH;
    int o = threadIdx.x;  // 128
    int nend = min(n0 + CH, N_NODES);
    if (n0 >= N_NODES) return;
    int curg = batch[n0];
    float run = 0.f;
    for (int n = n0; n < nend; ++n) {
        int g = batch[n];
        if (g != curg) {
            atomicAdd(&acc[(size_t)curg * HID + o], run);
            run = 0.f;
            curg = g;
        }
        run += h[(size_t)n * HID + o];
    }
    atomicAdd(&acc[(size_t)curg * HID + o], run);
}

__global__ void k_final(const float* __restrict__ acc, const float* __restrict__ cntG,
                        float* __restrict__ out) {
    int idx = blockIdx.x * blockDim.x + threadIdx.x;
    if (idx >= N_GRAPHS * HID) return;
    int g = idx >> 7;
    out[idx] = acc[idx] / fmaxf(cntG[g], 1.0f);
}

extern "C" void kernel_launch(void* const* d_in, const int* in_sizes, int n_in,
                              void* d_out, int out_size, void* d_ws, size_t ws_size,
                              hipStream_t stream) {
    const int*   x         = (const int*)d_in[0];
    const int*   edge_index= (const int*)d_in[1];
    const int*   etype     = (const int*)d_in[2];
    const int*   batch     = (const int*)d_in[3];
    const float* node_emb  = (const float*)d_in[4];
    const float* comp1     = (const float*)d_in[5];
    const float* basis1    = (const float*)d_in[6];
    const float* root1     = (const float*)d_in[7];
    const float* bias1     = (const float*)d_in[8];
    const float* comp2     = (const float*)d_in[9];
    const float* basis2    = (const float*)d_in[10];
    const float* root2     = (const float*)d_in[11];
    const float* bias2     = (const float*)d_in[12];
    float* out = (float*)d_out;

    const int* src = edge_index;            // [E]
    const int* dst = edge_index + N_EDGES;  // [E]

    float* ws   = (float*)d_ws;
    float* W1   = ws + OFF_W1;
    float* W2   = ws + OFF_W2;
    float* cnt  = ws + OFF_CNT;
    float* h1   = ws + OFF_H1;
    float* h2   = ws + OFF_H2;
    float* cntG = ws + OFF_CNTG;
    float* pool = ws + OFF_POOL;

    // zero the atomic accumulators (h1/h2 are fully written by k_root first)
    hipMemsetAsync(cnt, 0, (size_t)N_NODES * N_REL * sizeof(float), stream);
    hipMemsetAsync(cntG, 0, (size_t)(N_GRAPHS + N_GRAPHS * HID) * sizeof(float), stream);

    // weights from basis decomposition
    {
        int total1 = N_REL * EMB * HID;
        k_compute_W<<<(total1 + 255) / 256, 256, 0, stream>>>(comp1, basis1, W1, EMB * HID);
        int total2 = N_REL * HID * HID;
        k_compute_W<<<(total2 + 255) / 256, 256, 0, stream>>>(comp2, basis2, W2, HID * HID);
    }

    // per (dst, rel) edge counts
    k_count<<<(N_EDGES + 255) / 256, 256, 0, stream>>>(dst, etype, cnt);

    // ---- layer 1 ----
    k_root<EMB><<<N_NODES, HID, 0, stream>>>(node_emb, x, root1, bias1, h1);
    k_edge<EMB><<<60000, HID, 0, stream>>>(node_emb, x, src, dst, etype, W1, cnt, h1);
    k_relu<<<(N_NODES * HID + 255) / 256, 256, 0, stream>>>(h1, (size_t)N_NODES * HID);

    // ---- layer 2 ----
    k_root<HID><<<N_NODES, HID, 0, stream>>>(h1, nullptr, root2, bias2, h2);
    k_edge<HID><<<60000, HID, 0, stream>>>(h1, nullptr, src, dst, etype, W2, cnt, h2);
    k_relu<<<(N_NODES * HID + 255) / 256, 256, 0, stream>>>(h2, (size_t)N_NODES * HID);

    // ---- global mean pool ----
    k_gcount<<<(N_NODES + 255) / 256, 256, 0, stream>>>(batch, cntG);
    k_pool<<<(N_NODES + 511) / 512, HID, 0, stream>>>(h2, batch, pool);
    k_final<<<(N_GRAPHS * HID + 255) / 256, 256, 0, stream>>>(pool, cntG, out);
}